// Round 7
// baseline (459.148 us; speedup 1.0000x reference)
//
#include <hip/hip_runtime.h>
#include <hip/hip_bf16.h>

typedef __bf16 bf16;
typedef __bf16 bf16x8 __attribute__((ext_vector_type(8)));
typedef float f32x4 __attribute__((ext_vector_type(4)));

#define MFMA16(a, b, c) __builtin_amdgcn_mfma_f32_16x16x32_bf16((a), (b), (c), 0, 0, 0)

// Problem: B=2, L=4096, D=1024, H=8, Hd=128, CHUNK=64, NCHUNK=64
// gamma_h = 1 - 2^(-5-h).  Inputs fp32, OUTPUT fp32.

// async 16B global->LDS (gfx950). LDS dest is wave-uniform base + lane*16.
__device__ __forceinline__ void g2l16(const bf16* g, bf16* l) {
  __builtin_amdgcn_global_load_lds(
      (const __attribute__((address_space(1))) void*)g,
      (__attribute__((address_space(3))) void*)l, 16, 0, 0);
}

// ---------------------------------------------------------------------------
// prep: z<4 -> transpose+cvt weight z (Wt[z][n][k]=bf16(W[k][n]));
//       z==4 -> bulk fp32->bf16 convert of X.
// ---------------------------------------------------------------------------
__global__ __launch_bounds__(256) void prep(
    const float* __restrict__ X, const float* __restrict__ Wq,
    const float* __restrict__ Wk, const float* __restrict__ Wv,
    const float* __restrict__ Wo, bf16* __restrict__ Wt,
    bf16* __restrict__ Xb) {
  const int tid = threadIdx.x;
  if (blockIdx.z == 4) {
#pragma unroll
    for (int it = 0; it < 16; ++it) {
      const size_t i = (((size_t)blockIdx.x * 16 + it) * 256 + tid) * 8;
      float4 a = *(const float4*)&X[i];
      float4 b = *(const float4*)&X[i + 4];
      union { bf16 h[8]; uint4 u; } p;
      p.h[0] = (bf16)a.x; p.h[1] = (bf16)a.y; p.h[2] = (bf16)a.z; p.h[3] = (bf16)a.w;
      p.h[4] = (bf16)b.x; p.h[5] = (bf16)b.y; p.h[6] = (bf16)b.z; p.h[7] = (bf16)b.w;
      *(uint4*)&Xb[i] = p.u;
    }
    return;
  }
  __shared__ bf16 t[64 * 72];
  const float* src = (blockIdx.z == 0) ? Wq : (blockIdx.z == 1) ? Wk
                     : (blockIdx.z == 2) ? Wv : Wo;
  bf16* dst = Wt + (size_t)blockIdx.z * 1024 * 1024;
  const int k0 = (blockIdx.x >> 4) * 64, n0 = (blockIdx.x & 15) * 64;
#pragma unroll
  for (int s = 0; s < 4; ++s) {
    int u = tid + s * 256;
    int r = u >> 4, c4 = (u & 15) * 4;
    float4 f = *(const float4*)&src[(size_t)(k0 + r) * 1024 + n0 + c4];
    t[r * 72 + c4 + 0] = (bf16)f.x;
    t[r * 72 + c4 + 1] = (bf16)f.y;
    t[r * 72 + c4 + 2] = (bf16)f.z;
    t[r * 72 + c4 + 3] = (bf16)f.w;
  }
  __syncthreads();
#pragma unroll
  for (int s = 0; s < 2; ++s) {
    int u = tid + s * 256;
    int r = u >> 3, cc = u & 7;
    union { bf16 h[8]; uint4 u4; } pk;
#pragma unroll
    for (int j = 0; j < 8; ++j) pk.h[j] = t[(cc * 8 + j) * 72 + r];
    *(uint4*)&dst[(size_t)(n0 + r) * 1024 + k0 + cc * 8] = pk.u4;
  }
}

// ---------------------------------------------------------------------------
// GEMM: C = alpha * (A @ Bt^T).  128x128 tile, BK=64, global_load_lds(16B)
// staging with XOR swizzle (0 bank conflicts, measured r4/r5).
// MODE==1 (QKV): z=0 -> q normal (alpha); z=1 -> k normal AND kT; z=2 -> vT.
//   kT/vT per (bh,chunk) g, layout Tp[g*8192 + d*64 + c] (direct scatter —
//   measured faster than LDS-roundtrip epilogue, r5 vs r6).
// MODE==0: plain fp32 store to C.
// ---------------------------------------------------------------------------
template <typename TC, int MODE>
__global__ __launch_bounds__(256) void gemm_lds(
    const bf16* __restrict__ A, const bf16* __restrict__ Bt,
    TC* __restrict__ C, bf16* __restrict__ kTb, bf16* __restrict__ vTb,
    float alpha) {
  __shared__ bf16 lA[128 * 64];
  __shared__ bf16 lB[128 * 64];
  const int m0 = blockIdx.x * 128, n0 = blockIdx.y * 128;
  if (MODE) {
    Bt += (size_t)blockIdx.z * 1024 * 1024;
    if (blockIdx.z != 0) alpha = 1.0f;
  }
  const int tid = threadIdx.x;
  const int w = tid >> 6, lane = tid & 63, lr = lane & 15, quad = lane >> 4;
  const int wm = w >> 1, wn = w & 1;

  const int srow = w * 32 + (lane >> 3);
  const int clog = (lane & 7) ^ ((lane >> 3) & 7);
  const bf16* gA = A + (size_t)(m0 + srow) * 1024 + clog * 8;
  const bf16* gB = Bt + (size_t)(n0 + srow) * 1024 + clog * 8;

  f32x4 acc[4][4] = {};

  for (int it = 0; it < 16; ++it) {
    const int k0 = it * 64;
#pragma unroll
    for (int is = 0; is < 4; ++is) {
      g2l16(gA + (size_t)is * 8 * 1024 + k0, &lA[(w * 32 + is * 8) * 64]);
      g2l16(gB + (size_t)is * 8 * 1024 + k0, &lB[(w * 32 + is * 8) * 64]);
    }
    __syncthreads();
#pragma unroll
    for (int kk = 0; kk < 2; ++kk) {
      bf16x8 af[4], bfv[4];
#pragma unroll
      for (int i = 0; i < 4; ++i) {
        const int m = wm * 64 + i * 16 + lr;
        af[i] = *(bf16x8*)&lA[m * 64 + (((kk * 4 + quad) ^ (lr & 7)) * 8)];
      }
#pragma unroll
      for (int j = 0; j < 4; ++j) {
        const int n = wn * 64 + j * 16 + lr;
        bfv[j] = *(bf16x8*)&lB[n * 64 + (((kk * 4 + quad) ^ (lr & 7)) * 8)];
      }
#pragma unroll
      for (int i = 0; i < 4; ++i)
#pragma unroll
        for (int j = 0; j < 4; ++j)
          acc[i][j] = MFMA16(af[i], bfv[j], acc[i][j]);
    }
    __syncthreads();
  }
  // Epilogue. D layout col=lane&15, row=quad*4+r.
#pragma unroll
  for (int i = 0; i < 4; ++i) {
#pragma unroll
    for (int j = 0; j < 4; ++j) {
      const int row = m0 + wm * 64 + i * 16 + quad * 4;
      const int col = n0 + wn * 64 + j * 16 + lr;
      if (MODE == 0 || blockIdx.z < 2) {
        TC* Cz = C + (MODE ? (size_t)blockIdx.z * 8192 * 1024 : 0);
#pragma unroll
        for (int r = 0; r < 4; ++r)
          Cz[(size_t)(row + r) * 1024 + col] = (TC)(acc[i][j][r] * alpha);
      }
      if (MODE == 1 && blockIdx.z >= 1) {
        bf16* Tp = (blockIdx.z == 1) ? kTb : vTb;
        const int b = row >> 12, pos = row & 4095;
        const int n = pos >> 6, c0 = pos & 63;
        const int h = col >> 7, d = col & 127;
        union { bf16 h4[4]; uint2 u2; } pk;
#pragma unroll
        for (int r = 0; r < 4; ++r) pk.h4[r] = (bf16)acc[i][j][r];
        *(uint2*)&Tp[((size_t)((b * 8 + h) * 64 + n)) * 8192 + d * 64 + c0] = pk.u2;
      }
    }
  }
}

// ---------------------------------------------------------------------------
// Fused retention: replaces chunk_kv + scan_state + chunk_out.
// Grid 32 = (bh 16) x (dv-half 2); block marches 64 chunks serially.
// State S^T[dv16][dk128] fp32 in regs per wave (wave-private), bf16 LDS
// mirror (XOR swizzle) feeds q@S B-frags.  kT/vT staged double-buffered
// with one-chunk-ahead prefetch.  Per chunk per wave: 16 qS + 16 P + 8 PV +
// 16 T-update MFMAs.
// ---------------------------------------------------------------------------
__global__ __launch_bounds__(256) void retention(
    const bf16* __restrict__ qb, const bf16* __restrict__ kb,
    const bf16* __restrict__ kTb, const bf16* __restrict__ vTb,
    bf16* __restrict__ ob) {
  __shared__ bf16 sKT[2][128 * 64];  // [dk][c swz], decay folded
  __shared__ bf16 sVT[2][64 * 64];   // [dv-local][c swz]
  __shared__ bf16 sS[64 * 128];      // S^T mirror [dv-local][dk swz]
  __shared__ bf16 sP[64 * 64];       // masked P [ci][cj swz]
  const int blk = blockIdx.x, bh = blk >> 1, dvh = blk & 1;
  const int b = bh >> 3, h = bh & 7;
  const float lg = log2f(1.0f - exp2f(-5.0f - (float)h));
  const float g64 = exp2f(64.0f * lg), gam = exp2f(lg), ginv = exp2f(-lg);
  const int tid = threadIdx.x;
  const int w = tid >> 6, lane = tid & 63, lr = lane & 15, quad = lane >> 4;

  // zero the S mirror
  for (int i = tid; i < 1024; i += 256) ((uint4*)sS)[i] = make_uint4(0, 0, 0, 0);

  f32x4 ST[8] = {};     // S^T fp32 master, wave rows [w*16, w*16+16) x dk 128
  uint4 pk[4], pv[2];   // staging in flight

  // prologue: load + write chunk 0
  {
    const bf16* kg = kTb + (size_t)(bh * 64 + 0) * 8192;
    const bf16* vg = vTb + (size_t)(bh * 64 + 0) * 8192 + dvh * 4096;
#pragma unroll
    for (int s = 0; s < 4; ++s) {
      int idx = tid + s * 256;
      pk[s] = *(const uint4*)&kg[(idx >> 3) * 64 + (idx & 7) * 8];
    }
#pragma unroll
    for (int s = 0; s < 2; ++s) {
      int idx = tid + s * 256;
      pv[s] = *(const uint4*)&vg[(idx >> 3) * 64 + (idx & 7) * 8];
    }
#pragma unroll
    for (int s = 0; s < 4; ++s) {
      int idx = tid + s * 256, d = idx >> 3, c8 = idx & 7;
      union { uint4 u4; bf16 h8[8]; } kv; kv.u4 = pk[s];
      float e = exp2f((float)(63 - c8 * 8) * lg);
      union { bf16 h8[8]; uint4 u4; } o;
#pragma unroll
      for (int jj = 0; jj < 8; ++jj) { o.h8[jj] = (bf16)((float)kv.h8[jj] * e); e *= ginv; }
      *(uint4*)&sKT[0][d * 64 + ((c8 ^ (d & 7)) * 8)] = o.u4;
    }
#pragma unroll
    for (int s = 0; s < 2; ++s) {
      int idx = tid + s * 256, d = idx >> 3, c8 = idx & 7;
      *(uint4*)&sVT[0][d * 64 + ((c8 ^ (d & 7)) * 8)] = pv[s];
    }
  }
  __syncthreads();

  for (int n = 0; n < 64; ++n) {
    const int buf = n & 1;
    // prefetch next chunk's kT/vT into regs
    {
      const int np = (n < 63) ? n + 1 : 63;
      const bf16* kg = kTb + (size_t)(bh * 64 + np) * 8192;
      const bf16* vg = vTb + (size_t)(bh * 64 + np) * 8192 + dvh * 4096;
#pragma unroll
      for (int s = 0; s < 4; ++s) {
        int idx = tid + s * 256;
        pk[s] = *(const uint4*)&kg[(idx >> 3) * 64 + (idx & 7) * 8];
      }
#pragma unroll
      for (int s = 0; s < 2; ++s) {
        int idx = tid + s * 256;
        pv[s] = *(const uint4*)&vg[(idx >> 3) * 64 + (idx & 7) * 8];
      }
    }
    const size_t rowbase = (size_t)(b * 4096 + n * 64) * 1024 + h * 128;
    const bf16* qc = qb + rowbase;
    const bf16* kc = kb + rowbase;

    // --- qS: o_inter = q @ S_prev (B from sS mirror, wave-private rows) ---
    f32x4 oin[4] = {}, oac[4] = {};
#pragma unroll
    for (int kk = 0; kk < 4; ++kk) {
      bf16x8 bS = *(bf16x8*)&sS[(w * 16 + lr) * 128 + (((kk * 4 + quad) ^ (lr & 7)) * 8)];
#pragma unroll
      for (int i = 0; i < 4; ++i) {
        bf16x8 aq = *(const bf16x8*)&qc[(size_t)(i * 16 + lr) * 1024 + kk * 32 + quad * 8];
        oin[i] = MFMA16(aq, bS, oin[i]);
      }
    }

    // --- P = q @ k^T (wave w computes cj in [w*16, w*16+16)) ---
    f32x4 p[4] = {};
#pragma unroll
    for (int kk = 0; kk < 4; ++kk) {
      bf16x8 bk = *(const bf16x8*)&kc[(size_t)(w * 16 + lr) * 1024 + kk * 32 + quad * 8];
#pragma unroll
      for (int i = 0; i < 4; ++i) {
        bf16x8 aq = *(const bf16x8*)&qc[(size_t)(i * 16 + lr) * 1024 + kk * 32 + quad * 8];
        p[i] = MFMA16(aq, bk, p[i]);
      }
    }
    const int cj = w * 16 + lr;
#pragma unroll
    for (int i = 0; i < 4; ++i) {
#pragma unroll
      for (int r = 0; r < 4; ++r) {
        const int row = i * 16 + quad * 4 + r;
        const int diff = row - cj;
        const float val = (diff >= 0) ? p[i][r] * exp2f((float)diff * lg) : 0.0f;
        sP[row * 64 + (((cj >> 3) ^ (row & 7)) * 8) + (cj & 7)] = (bf16)val;
      }
    }
    __syncthreads();  // B1: sP ready

    // --- PV: o_intra (wave dv rows [w*16,+16)) ---
#pragma unroll
    for (int kk = 0; kk < 2; ++kk) {
      bf16x8 bV = *(bf16x8*)&sVT[buf][(w * 16 + lr) * 64 + (((kk * 4 + quad) ^ (lr & 7)) * 8)];
#pragma unroll
      for (int i = 0; i < 4; ++i) {
        bf16x8 aP = *(bf16x8*)&sP[(i * 16 + lr) * 64 + (((kk * 4 + quad) ^ (lr & 7)) * 8)];
        oac[i] = MFMA16(aP, bV, oac[i]);
      }
    }

    // --- T-update: S = g64*S + vT @ kT(decayed) ---
#pragma unroll
    for (int nt = 0; nt < 8; ++nt) {
#pragma unroll
      for (int r = 0; r < 4; ++r) ST[nt][r] *= g64;
    }
#pragma unroll
    for (int kk2 = 0; kk2 < 2; ++kk2) {
      bf16x8 aV = *(bf16x8*)&sVT[buf][(w * 16 + lr) * 64 + (((kk2 * 4 + quad) ^ (lr & 7)) * 8)];
#pragma unroll
      for (int nt = 0; nt < 8; ++nt) {
        bf16x8 bK = *(bf16x8*)&sKT[buf][(nt * 16 + lr) * 64 + (((kk2 * 4 + quad) ^ (lr & 7)) * 8)];
        ST[nt] = MFMA16(aV, bK, ST[nt]);
      }
    }
    // write bf16 mirror (wave-private rows; same-wave RAW handled by lgkmcnt)
#pragma unroll
    for (int nt = 0; nt < 8; ++nt) {
#pragma unroll
      for (int r = 0; r < 4; ++r) {
        const int dv = w * 16 + quad * 4 + r;
        const int dk = nt * 16 + lr;
        sS[dv * 128 + (((dk >> 3) ^ (dv & 7)) * 8) + (dk & 7)] = (bf16)ST[nt][r];
      }
    }

    // --- combine + store o ---
    bf16* oc = ob + rowbase + dvh * 64 + w * 16;
#pragma unroll
    for (int i = 0; i < 4; ++i) {
      float d = exp2f((float)(i * 16 + quad * 4 + 1) * lg);
#pragma unroll
      for (int r = 0; r < 4; ++r) {
        const int row = i * 16 + quad * 4 + r;
        oc[(size_t)row * 1024 + lr] = (bf16)(oac[i][r] + d * oin[i][r]);
        d *= gam;
      }
    }

    // --- stage next chunk into the other buffer ---
    const int nb = buf ^ 1;
#pragma unroll
    for (int s = 0; s < 4; ++s) {
      int idx = tid + s * 256, d = idx >> 3, c8 = idx & 7;
      union { uint4 u4; bf16 h8[8]; } kv; kv.u4 = pk[s];
      float e = exp2f((float)(63 - c8 * 8) * lg);
      union { bf16 h8[8]; uint4 u4; } o;
#pragma unroll
      for (int jj = 0; jj < 8; ++jj) { o.h8[jj] = (bf16)((float)kv.h8[jj] * e); e *= ginv; }
      *(uint4*)&sKT[nb][d * 64 + ((c8 ^ (d & 7)) * 8)] = o.u4;
    }
#pragma unroll
    for (int s = 0; s < 2; ++s) {
      int idx = tid + s * 256, d = idx >> 3, c8 = idx & 7;
      *(uint4*)&sVT[nb][d * 64 + ((c8 ^ (d & 7)) * 8)] = pv[s];
    }
    __syncthreads();  // B2: next buffer ready, sP consumed
  }
}

// ---------------------------------------------------------------------------
extern "C" void kernel_launch(void* const* d_in, const int* in_sizes, int n_in,
                              void* d_out, int out_size, void* d_ws,
                              size_t ws_size, hipStream_t stream) {
  const float* X  = (const float*)d_in[0];
  const float* Wq = (const float*)d_in[2];
  const float* Wk = (const float*)d_in[3];
  const float* Wv = (const float*)d_in[4];
  const float* Wo = (const float*)d_in[5];

  char* ws = (char*)d_ws;
  const size_t MB = 1024 * 1024;
  bf16* qb  = (bf16*)(ws);              // 16 MiB
  bf16* kb  = (bf16*)(ws + 16 * MB);    // 16 MiB (normal layout)
  bf16* kTb = (bf16*)(ws + 32 * MB);    // 16 MiB (per-chunk transposed)
  bf16* vTb = (bf16*)(ws + 48 * MB);    // 16 MiB (per-chunk transposed)
  bf16* Wt  = (bf16*)(ws + 64 * MB);    // 8 MiB
  bf16* Xb  = (bf16*)(ws + 72 * MB);    // 16 MiB; dead after QKV gemm
  bf16* ob  = Xb;                       // alias: ob written after Xb last use

  prep<<<dim3(256, 1, 5), 256, 0, stream>>>(X, Wq, Wk, Wv, Wo, Wt, Xb);

  const float qscale = 0.08838834764831845f;  // 128^-0.5
  gemm_lds<bf16, 1><<<dim3(64, 8, 3), 256, 0, stream>>>(Xb, Wt, qb, kTb, vTb,
                                                        qscale);

  retention<<<32, 256, 0, stream>>>(qb, kb, kTb, vTb, ob);

  gemm_lds<float, 0><<<dim3(64, 8), 256, 0, stream>>>(
      ob, Wt + (size_t)3 * 1024 * 1024, (float*)d_out, nullptr, nullptr, 1.0f);
}